// Round 4
// baseline (364.633 us; speedup 1.0000x reference)
//
#include <hip/hip_runtime.h>
#include <hip/hip_fp16.h>
#include <math.h>

// GCN encoder, N=100000, E=1600000, C_IN=32, C_H=C_OUT=64, G=64.
// CSR build via two-level LDS counting sort (NO global atomics).
// em weight = ew*dis[dst]; dis[src] folded into features.
// R12: TRANSFORM-FIRST layers 2/3 (agg(h)W == agg(hW)): k_mm64 GEMM +
// lean k_agg64 (no per-node matvec). Cured the w[64]-remat disease
// (compiler re-loads per-lane W each node; VGPR stuck at 60).
// R13: (1) layer 1 split the same way: k_agg32 = pure 32-ch aggregate
// (no W), k_mm32act = N*32*64 GEMM w/ W1+bias+silu+dis fused (W in LDS,
// broadcast reads). (2) agg kernels: contiguous 8-node chunks per wave
// + windowed edge-meta staging — em is CSR-contiguous per wave, so 1-2
// coalesced 128-edge loads replace per-node guarded loads; rowptr for
// the chunk loaded once and shfl-broadcast. Removes 2 serial memory
// latencies per node (kernels are latency-bound: VALU 33%, HBM 18%).

#define NB   256        // dst buckets (512 nodes each; supports N < 131072)
#define PBLK 1024       // partition blocks
#define FIXP_SCALE 1048576.0f   // 2^20
#define FIXP_MASK  ((1ULL << 40) - 1)

__device__ __forceinline__ int lower_bound_i(const int* __restrict__ a, int n, int v) {
    int lo = 0, hi = n;
    while (lo < hi) {
        int m = (lo + hi) >> 1;
        if (a[m] < v) lo = m + 1; else hi = m;
    }
    return lo;
}

// A1: per-block histogram over 256 dst-buckets (LDS atomics only)
__global__ __launch_bounds__(256) void k_bhist(const int* __restrict__ dst,
                                               int* __restrict__ hcnt, int e) {
    __shared__ int hist[NB];
    int tid = threadIdx.x, blk = blockIdx.x;
    hist[tid] = 0;
    __syncthreads();
    int chunk = (e + PBLK - 1) / PBLK;
    int lo = blk * chunk, hi = min(e, lo + chunk);
    for (int i = lo + tid; i < hi; i += 256)
        atomicAdd(&hist[dst[i] >> 9], 1);
    __syncthreads();
    hcnt[tid * PBLK + blk] = hist[tid];   // [bucket][block] layout
}

// A2a: per-bucket exclusive scan across the PBLK block-counts (in place) + totals
__global__ __launch_bounds__(256) void k_bscan(int* __restrict__ hcnt,
                                               int* __restrict__ btot) {
    __shared__ int s[256];
    int b = blockIdx.x, tid = threadIdx.x;
    int* row = hcnt + b * PBLK;
    int a0 = row[4 * tid], a1 = row[4 * tid + 1], a2 = row[4 * tid + 2], a3 = row[4 * tid + 3];
    int tsum = a0 + a1 + a2 + a3;
    s[tid] = tsum;
    __syncthreads();
    for (int off = 1; off < 256; off <<= 1) {
        int t = (tid >= off) ? s[tid - off] : 0;
        __syncthreads();
        s[tid] += t;
        __syncthreads();
    }
    int ex = s[tid] - tsum;
    row[4 * tid] = ex;
    row[4 * tid + 1] = ex + a0;
    row[4 * tid + 2] = ex + a0 + a1;
    row[4 * tid + 3] = ex + a0 + a1 + a2;
    if (tid == 255) btot[b] = s[255];
}

// A2b: scan bucket totals -> bucket_base[NB+1]; also rowptr[n]=e
__global__ __launch_bounds__(256) void k_bbase(const int* __restrict__ btot,
                                               int* __restrict__ bbase,
                                               int* __restrict__ rowptr, int n, int e) {
    __shared__ int s[256];
    int tid = threadIdx.x;
    int v = btot[tid];
    s[tid] = v;
    __syncthreads();
    for (int off = 1; off < 256; off <<= 1) {
        int t = (tid >= off) ? s[tid - off] : 0;
        __syncthreads();
        s[tid] += t;
        __syncthreads();
    }
    bbase[tid] = s[tid] - v;
    if (tid == 255) bbase[NB] = s[255];   // == e
    if (tid == 0) rowptr[n] = e;
}

// A3: partition edges into buckets; pos from LDS cursor (no global atomics)
__global__ __launch_bounds__(256) void k_bpart(const int* __restrict__ src,
                                               const int* __restrict__ dst,
                                               const float* __restrict__ ew,
                                               const int* __restrict__ hcnt,
                                               const int* __restrict__ bbase,
                                               int2* __restrict__ bedge, int e) {
    __shared__ int cur[NB];
    int tid = threadIdx.x, blk = blockIdx.x;
    cur[tid] = bbase[tid] + hcnt[tid * PBLK + blk];
    __syncthreads();
    int chunk = (e + PBLK - 1) / PBLK;
    int lo = blk * chunk, hi = min(e, lo + chunk);
    for (int i = lo + tid; i < hi; i += 256) {
        int d = dst[i];
        int pos = atomicAdd(&cur[d >> 9], 1);            // LDS atomic
        bedge[pos] = make_int2(src[i] | ((d & 511) << 17), __float_as_int(ew[i]));
    }
}

// B: per-bucket (512 nodes): LDS packed cnt + fixp sum(ew) -> dis, rowptr,
// then scatter (src, ew*dis[d]) grouped per node into em. No global atomics.
__global__ __launch_bounds__(256) void k_bucket(const int2* __restrict__ bedge,
                                                const int* __restrict__ bbase,
                                                float* __restrict__ dis,
                                                int* __restrict__ rowptr,
                                                int2* __restrict__ em, int n) {
    __shared__ unsigned long long pk[512];
    __shared__ int cnt[512];
    __shared__ int scn[512];
    __shared__ float sdis[512];
    __shared__ int cur[512];
    int b = blockIdx.x, tid = threadIdx.x;
    int e0 = bbase[b], e1 = bbase[b + 1];
    pk[tid] = 0ULL; pk[tid + 256] = 0ULL;
    __syncthreads();
    for (int i = e0 + tid; i < e1; i += 256) {
        int2 v = bedge[i];
        int dlo = (v.x >> 17) & 511;
        unsigned long long p =
            (1ULL << 40) | (unsigned long long)(__int_as_float(v.y) * FIXP_SCALE);
        atomicAdd(&pk[dlo], p);                          // LDS atomic
    }
    __syncthreads();
#pragma unroll
    for (int k = 0; k < 2; ++k) {
        int i = tid + k * 256;
        unsigned long long v = pk[i];
        int c = (int)(v >> 40);
        cnt[i] = c; scn[i] = c;
        sdis[i] = rsqrtf(1.0f + (float)(v & FIXP_MASK) * (1.0f / FIXP_SCALE));
    }
    __syncthreads();
    // 512-entry inclusive scan, 2 elems/thread, read-all-then-write-all
    for (int off = 1; off < 512; off <<= 1) {
        int i0 = tid, i1 = tid + 256;
        int v0 = (i0 >= off) ? scn[i0 - off] : 0;
        int v1 = (i1 >= off) ? scn[i1 - off] : 0;
        __syncthreads();
        scn[i0] += v0; scn[i1] += v1;
        __syncthreads();
    }
#pragma unroll
    for (int k = 0; k < 2; ++k) {
        int i = tid + k * 256;
        int rb = e0 + scn[i] - cnt[i];                   // exclusive
        cur[i] = rb;
        int node = (b << 9) + i;
        if (node < n) { rowptr[node] = rb; dis[node] = sdis[i]; }
    }
    __syncthreads();
    for (int i = e0 + tid; i < e1; i += 256) {
        int2 v = bedge[i];
        int dlo = (v.x >> 17) & 511;
        int pos = atomicAdd(&cur[dlo], 1);               // LDS atomic
        float w = __int_as_float(v.y) * sdis[dlo];
        em[pos] = make_int2(v.x & 0x1FFFF, __float_as_int(w));
    }
}

// hs = fp16(dis * x)  (layer-1 feature pre-scale, 32 channels)
__global__ void k_scale(const float* __restrict__ x, const float* __restrict__ dis,
                        __half* __restrict__ hs, int total) {
    int idx = blockIdx.x * blockDim.x + threadIdx.x;
    if (idx < total) hs[idx] = __float2half(x[idx] * dis[idx >> 5]);
}

__device__ __forceinline__ float2 cvt_pair(unsigned int u) {
    __half2 h2 = *(__half2*)&u;
    return __half22float2(h2);
}

// R13: pure 32-ch aggregate. y0 = sum_e w_e hs[src] + di*hs[node].
// Wave owns 8 CONTIGUOUS nodes; their em range is contiguous -> windowed
// LDS staging (128 edges, coalesced). Lane = channel-pair c (16/row),
// wave quarters take edges mod 4 (4 edges per gather round).
__global__ __launch_bounds__(256, 4) void k_agg32(const __half* __restrict__ hs,
                                                  const int2* __restrict__ em,
                                                  const int* __restrict__ rowptr,
                                                  const float* __restrict__ dis,
                                                  __half* __restrict__ y0, int n) {
    __shared__ __align__(8) int2 sme[4][128];
    int lane = threadIdx.x & 63, wv = threadIdx.x >> 6;
    int c = lane & 15, quarter = lane >> 4;
    const unsigned int* h32 = (const unsigned int*)hs;
    int wid = (blockIdx.x * blockDim.x + threadIdx.x) >> 6;
    int n0 = wid * 8;
    if (n0 >= n) return;
    int cnt = min(8, n - n0);
    int rp = 0;
    if (lane <= cnt) rp = rowptr[n0 + lane];
    int hiw = __shfl(rp, cnt, 64);            // end of wave's edge range
    int wlo = 0, whi = 0;                     // staged window [wlo, whi)
    for (int k = 0; k < cnt; ++k) {
        int node = n0 + k;
        int lo = __shfl(rp, k, 64), hi = __shfl(rp, k + 1, 64);
        float2 acc = make_float2(0.0f, 0.0f);
        if (quarter == 0) {
            float di = dis[node];
            float2 hv = cvt_pair(h32[(unsigned)(node * 16 + c)]);
            acc.x = di * hv.x; acc.y = di * hv.y;        // self-loop: di^2*x = di*hs
        }
        int idx = lo;
        while (idx < hi) {
            if (idx >= whi) {                 // refill (wave-uniform)
                int i0 = idx + lane;
                if (i0 < hiw) sme[wv][lane] = em[i0];
                if (idx + 64 < hiw) {
                    int i1 = i0 + 64;
                    if (i1 < hiw) sme[wv][lane + 64] = em[i1];
                }
                wlo = idx; whi = idx + 128;
            }
            int base = idx - wlo;
            int take = min(hi, whi) - idx;    // 1..128 edges this pass
            for (int g = 0; g < take; g += 16) {
                int2 ev[4]; unsigned int hv[4]; int pr[4];
#pragma unroll
                for (int t = 0; t < 4; ++t) {
                    int p = g + 4 * t + quarter;
                    pr[t] = p < take;
                    int pc = pr[t] ? p : 0;               // clamp: stay in window
                    ev[t] = sme[wv][base + pc];           // 4-way bcast, no conflict
                }
#pragma unroll
                for (int t = 0; t < 4; ++t)
                    hv[t] = h32[(unsigned)(ev[t].x * 16 + c)];
#pragma unroll
                for (int t = 0; t < 4; ++t) {
                    float ww = pr[t] ? __int_as_float(ev[t].y) : 0.0f;
                    float2 hf = cvt_pair(hv[t]);
                    acc.x = fmaf(ww, hf.x, acc.x);
                    acc.y = fmaf(ww, hf.y, acc.y);
                }
            }
            idx += take;
        }
        // cross-quarter reduce (q0+=q2, q1+=q3; then q0+=q1)
        acc.x += __shfl_down(acc.x, 32, 64);
        acc.y += __shfl_down(acc.y, 32, 64);
        acc.x += __shfl_down(acc.x, 16, 64);
        acc.y += __shfl_down(acc.y, 16, 64);
        if (quarter == 0)
            ((__half2*)y0)[(size_t)node * 16 + c] =
                __float22half2_rn(make_float2(acc.x, acc.y));
    }
}

// R13: h1' = silu(y0 @ W1 + b1) * dis.  N x 32 -> N x 64, one node/thread,
// W1 (8KB) + b1 in LDS, wave-uniform broadcast reads.
__global__ __launch_bounds__(256, 2) void k_mm32act(const __half* __restrict__ y0,
                                                    const float* __restrict__ W,
                                                    const float* __restrict__ bias,
                                                    const float* __restrict__ dis,
                                                    __half* __restrict__ out, int n) {
    __shared__ __align__(16) float sw[32 * 64 + 64];
#pragma unroll
    for (int i = 0; i < 8; ++i)
        sw[threadIdx.x + 256 * i] = W[threadIdx.x + 256 * i];
    if (threadIdx.x < 64) sw[2048 + threadIdx.x] = bias[threadIdx.x];
    __syncthreads();
    int node = blockIdx.x * 256 + threadIdx.x;
    if (node >= n) return;
    uint4 yp[4];
    const uint4* yrow = (const uint4*)(y0 + (size_t)node * 32);
#pragma unroll
    for (int i = 0; i < 4; ++i) yp[i] = yrow[i];
    const unsigned int* ypk = (const unsigned int*)yp;   // 16 half2
    float o[64];
#pragma unroll
    for (int j = 0; j < 64; ++j) o[j] = sw[2048 + j];
#pragma unroll
    for (int k2 = 0; k2 < 16; ++k2) {
        float2 yk = cvt_pair(ypk[k2]);
        const float4* r0 = (const float4*)&sw[(2 * k2) * 64];
        const float4* r1 = (const float4*)&sw[(2 * k2 + 1) * 64];
#pragma unroll
        for (int j4 = 0; j4 < 16; ++j4) {
            float4 w0 = r0[j4];
            float4 w1 = r1[j4];
            o[4 * j4 + 0] = fmaf(yk.y, w1.x, fmaf(yk.x, w0.x, o[4 * j4 + 0]));
            o[4 * j4 + 1] = fmaf(yk.y, w1.y, fmaf(yk.x, w0.y, o[4 * j4 + 1]));
            o[4 * j4 + 2] = fmaf(yk.y, w1.z, fmaf(yk.x, w0.z, o[4 * j4 + 2]));
            o[4 * j4 + 3] = fmaf(yk.y, w1.w, fmaf(yk.x, w0.w, o[4 * j4 + 3]));
        }
    }
    float dsc = dis[node];
    __half2* orow = (__half2*)(out + (size_t)node * 64);
#pragma unroll
    for (int j2 = 0; j2 < 32; ++j2) {
        float ox = o[2 * j2], oy = o[2 * j2 + 1];
        ox = ox / (1.0f + __expf(-ox)) * dsc;
        oy = oy / (1.0f + __expf(-oy)) * dsc;
        orow[j2] = __float22half2_rn(make_float2(ox, oy));
    }
}

// R12: z = y @ W  (N x 64 fp16 in, 64x64 fp32 W, N x 64 fp16 out).
__global__ __launch_bounds__(256, 2) void k_mm64(const __half* __restrict__ y,
                                                 const float* __restrict__ W,
                                                 __half* __restrict__ z, int n) {
    __shared__ __align__(16) float sw[64 * 64];     // 16 KB
#pragma unroll
    for (int i = 0; i < 16; ++i)
        sw[threadIdx.x + 256 * i] = W[threadIdx.x + 256 * i];
    __syncthreads();
    int node = blockIdx.x * 256 + threadIdx.x;
    if (node >= n) return;
    uint4 yp[8];
    const uint4* yrow = (const uint4*)(y + (size_t)node * 64);
#pragma unroll
    for (int i = 0; i < 8; ++i) yp[i] = yrow[i];
    const unsigned int* ypk = (const unsigned int*)yp;   // 32 half2
    float o[64];
#pragma unroll
    for (int j = 0; j < 64; ++j) o[j] = 0.0f;
#pragma unroll
    for (int k2 = 0; k2 < 32; ++k2) {
        float2 yk = cvt_pair(ypk[k2]);
        const float4* r0 = (const float4*)&sw[(2 * k2) * 64];
        const float4* r1 = (const float4*)&sw[(2 * k2 + 1) * 64];
#pragma unroll
        for (int j4 = 0; j4 < 16; ++j4) {
            float4 w0 = r0[j4];
            float4 w1 = r1[j4];
            o[4 * j4 + 0] = fmaf(yk.y, w1.x, fmaf(yk.x, w0.x, o[4 * j4 + 0]));
            o[4 * j4 + 1] = fmaf(yk.y, w1.y, fmaf(yk.x, w0.y, o[4 * j4 + 1]));
            o[4 * j4 + 2] = fmaf(yk.y, w1.z, fmaf(yk.x, w0.z, o[4 * j4 + 2]));
            o[4 * j4 + 3] = fmaf(yk.y, w1.w, fmaf(yk.x, w0.w, o[4 * j4 + 3]));
        }
    }
    __half2* zrow = (__half2*)(z + (size_t)node * 64);
#pragma unroll
    for (int j2 = 0; j2 < 32; ++j2)
        zrow[j2] = __float22half2_rn(make_float2(o[2 * j2], o[2 * j2 + 1]));
}

// R12+R13: lean 64-ch aggregate on transformed z, windowed staging.
// out = [di*] silu( sum_e w_e z[src] + di*z[node] + bias ).
template <bool SCALE, typename OUT>
__global__ __launch_bounds__(256, 4) void k_agg64(const __half* __restrict__ z,
                                                  const int2* __restrict__ em,
                                                  const int* __restrict__ rowptr,
                                                  const float* __restrict__ dis,
                                                  const float* __restrict__ bias,
                                                  OUT* __restrict__ out, int n) {
    __shared__ __align__(8) int2 sme[4][128];
    int lane = threadIdx.x & 63, wv = threadIdx.x >> 6;
    int c = lane & 31, half = lane >> 5;
    const unsigned int* h32 = (const unsigned int*)z;
    float2 bv2 = ((const float2*)bias)[c];
    int wid = (blockIdx.x * blockDim.x + threadIdx.x) >> 6;
    int n0 = wid * 8;
    if (n0 >= n) return;
    int cnt = min(8, n - n0);
    int rp = 0;
    if (lane <= cnt) rp = rowptr[n0 + lane];
    int hiw = __shfl(rp, cnt, 64);
    int wlo = 0, whi = 0;
    for (int k = 0; k < cnt; ++k) {
        int node = n0 + k;
        int lo = __shfl(rp, k, 64), hi = __shfl(rp, k + 1, 64);
        float di = 0.0f;
        float2 acc = make_float2(0.0f, 0.0f);
        if (half == 0) {
            di = dis[node];
            float2 hv = cvt_pair(h32[(unsigned)(node * 32 + c)]);
            acc.x = di * hv.x; acc.y = di * hv.y;        // self-loop term
        }
        int idx = lo;
        while (idx < hi) {
            if (idx >= whi) {                 // refill (wave-uniform)
                int i0 = idx + lane;
                if (i0 < hiw) sme[wv][lane] = em[i0];
                if (idx + 64 < hiw) {
                    int i1 = i0 + 64;
                    if (i1 < hiw) sme[wv][lane + 64] = em[i1];
                }
                wlo = idx; whi = idx + 128;
            }
            int base = idx - wlo;
            int take = min(hi, whi) - idx;
            for (int g = 0; g < take; g += 16) {
                int2 ev[8]; unsigned int hv[8]; int pr[8];
#pragma unroll
                for (int t = 0; t < 8; ++t) {
                    int p = g + 2 * t + half;
                    pr[t] = p < take;
                    int pc = pr[t] ? p : 0;               // clamp: stay in window
                    ev[t] = sme[wv][base + pc];           // per-half bcast
                }
#pragma unroll
                for (int t = 0; t < 8; ++t)
                    hv[t] = h32[(unsigned)(ev[t].x * 32 + c)];
#pragma unroll
                for (int t = 0; t < 8; ++t) {
                    float ww = pr[t] ? __int_as_float(ev[t].y) : 0.0f;
                    float2 hf = cvt_pair(hv[t]);
                    acc.x = fmaf(ww, hf.x, acc.x);
                    acc.y = fmaf(ww, hf.y, acc.y);
                }
            }
            idx += take;
        }
        acc.x += __shfl_down(acc.x, 32, 64);
        acc.y += __shfl_down(acc.y, 32, 64);
        if (half == 0) {
            float ox = acc.x + bv2.x, oy = acc.y + bv2.y;
            ox = ox / (1.0f + __expf(-ox));
            oy = oy / (1.0f + __expf(-oy));
            if (SCALE) { ox *= di; oy *= di; }
            if (sizeof(OUT) == 2) {
                ((__half2*)out)[(size_t)node * 32 + c] =
                    __float22half2_rn(make_float2(ox, oy));
            } else {
                ((float2*)out)[(size_t)node * 32 + c] = make_float2(ox, oy);
            }
        }
    }
}

// pool phase 1: 128-row chunks, segment-flush atomics into acc[G*64]
__global__ void k_pool_partial(const float* __restrict__ h, const int* __restrict__ batch,
                               float* __restrict__ acc, int n) {
    int c = threadIdx.x & 63, r = threadIdx.x >> 6;
    int base = blockIdx.x * 128;
    int end = base + 128; if (end > n) end = n;
    float part = 0.0f;
    int cur = -1;
    for (int i = base + r; i < end; i += 4) {
        int g = batch[i];
        if (g != cur) {
            if (cur >= 0) atomicAdd(&acc[cur * 64 + c], part);
            part = 0.0f;
            cur = g;
        }
        part += h[(size_t)i * 64 + c];
    }
    if (cur >= 0) atomicAdd(&acc[cur * 64 + c], part);
}

// pool phase 2: divide by per-graph count
__global__ void k_pool_final(const float* __restrict__ acc, const int* __restrict__ batch,
                             float* __restrict__ out, int n) {
    int idx = blockIdx.x * blockDim.x + threadIdx.x;   // G*64 threads
    int g = idx >> 6;
    int lo = lower_bound_i(batch, n, g);
    int hi = lower_bound_i(batch, n, g + 1);
    int cnt = hi - lo;
    out[idx] = acc[idx] / (float)(cnt > 0 ? cnt : 1);
}

extern "C" void kernel_launch(void* const* d_in, const int* in_sizes, int n_in,
                              void* d_out, int out_size, void* d_ws, size_t ws_size,
                              hipStream_t stream) {
    const float* x   = (const float*)d_in[0];
    const float* ew  = (const float*)d_in[1];
    const float* W1  = (const float*)d_in[2];
    const float* b1  = (const float*)d_in[3];
    const float* W2  = (const float*)d_in[4];
    const float* b2  = (const float*)d_in[5];
    const float* W3  = (const float*)d_in[6];
    const float* b3  = (const float*)d_in[7];
    const int*   eidx  = (const int*)d_in[8];
    const int*   batch = (const int*)d_in[9];
    float* out = (float*)d_out;

    const int E = in_sizes[1];       // 1,600,000
    const int N = in_sizes[9];       // 100,000 (< 131072: fits 17-bit src pack)
    const int G = 64;
    const int* src = eidx;
    const int* dst = eidx + E;

    // workspace: A/B (fp16 features) double as CSR-build scratch
    // (bedge in A: E*8B == N*64*2B exactly; hcnt/btot in B); C holds the
    // fp16 y0 aggregate (layer 1) early, then the final fp32 layer.
    char* p = (char*)d_ws;
    __half* A     = (__half*)p;                p += (size_t)N * 64 * sizeof(__half);
    __half* B     = (__half*)p;                p += (size_t)N * 64 * sizeof(__half);
    float* C      = (float*)p;                 p += (size_t)N * 64 * sizeof(float);
    float* dis    = (float*)p;                 p += (size_t)N * sizeof(float);
    int*   rowptr = (int*)p;                   p += (size_t)(N + 1) * sizeof(int);
    int*   bbase  = (int*)p;                   p += (size_t)(NB + 1) * sizeof(int);
    float* acc    = (float*)p;                 p += (size_t)G * 64 * sizeof(float);
    p = (char*)(((uintptr_t)p + 7) & ~(uintptr_t)7);
    int2*  em     = (int2*)p;                  // E entries, 8B

    int2* bedge = (int2*)A;                    // E*8B == N*64*2B
    int*  hcnt  = (int*)B;                     // NB*PBLK*4B = 1MB
    int*  btot  = (int*)B + NB * PBLK;         // NB ints

    const int BT = 256;
    const int WAVES = (N + 7) / 8;             // 12500 waves, 8 contiguous nodes each
    const int AGG_BLOCKS = (WAVES + 3) / 4;    // 3125
    const int MM_BLOCKS = (N + 255) / 256;     // 391

    // --- CSR build: LDS counting sort, zero global atomics ---
    k_bhist<<<PBLK, 256, 0, stream>>>(dst, hcnt, E);
    k_bscan<<<NB, 256, 0, stream>>>(hcnt, btot);
    k_bbase<<<1, 256, 0, stream>>>(btot, bbase, rowptr, N, E);
    k_bpart<<<PBLK, 256, 0, stream>>>(src, dst, ew, hcnt, bbase, bedge, E);
    k_bucket<<<NB, 256, 0, stream>>>(bedge, bbase, dis, rowptr, em, N);

    // --- layer 1: hs = fp16(dis*x) -> B ; pure agg -> y0 (in C) ;
    //     h1' = silu(y0@W1+b1)*dis -> A ---
    k_scale<<<(N * 32 + BT - 1) / BT, BT, 0, stream>>>(x, dis, (__half*)B, N * 32);
    k_agg32<<<AGG_BLOCKS, BT, 0, stream>>>((__half*)B, em, rowptr, dis, (__half*)C, N);
    k_mm32act<<<MM_BLOCKS, BT, 0, stream>>>((__half*)C, W1, b1, dis, A, N);

    // --- layer 2: z2 = y1 @ W2 -> B ; agg+bias+silu*dis -> A ---
    k_mm64<<<MM_BLOCKS, BT, 0, stream>>>(A, W2, B, N);
    k_agg64<true, __half><<<AGG_BLOCKS, BT, 0, stream>>>(B, em, rowptr, dis, b2, A, N);

    // --- layer 3: z3 = y2 @ W3 -> B ; agg+bias+silu (fp32) -> C ---
    k_mm64<<<MM_BLOCKS, BT, 0, stream>>>(A, W3, B, N);
    k_agg64<false, float><<<AGG_BLOCKS, BT, 0, stream>>>(B, em, rowptr, dis, b3, C, N);

    // --- mean pool ---
    hipMemsetAsync(acc, 0, (size_t)G * 64 * sizeof(float), stream);
    k_pool_partial<<<(N + 127) / 128, BT, 0, stream>>>(C, batch, acc, N);
    k_pool_final<<<(G * 64) / BT, BT, 0, stream>>>(acc, batch, out, N);
}